// Round 1
// baseline (69.273 us; speedup 1.0000x reference)
//
#include <hip/hip_runtime.h>
#include <math.h>

// Problem constants: B=16, C=64, H=W=64, M=4096
#define KS 16            // split-K chunks per batch in cov kernel
#define CHUNK 256        // m-columns per chunk
#define PART_STRIDE 4160 // 64*64 partial S + 64 partial rowsums

// ---------------------------------------------------------------------------
// K1: per-(batch, chunk) partial Gram matrix S_ij = sum_m x_i[m] x_j[m]
//     plus partial row sums. LDS tile swizzled in 16B blocks so that
//     transposed-operand float4 reads are bank-conflict-free.
// ---------------------------------------------------------------------------
__global__ __launch_bounds__(256) void cov_partial_kernel(const float* __restrict__ x,
                                                          float* __restrict__ ws) {
    int blk = blockIdx.x;          // b*16 + ks
    int b = blk >> 4, ks = blk & 15;
    int m0 = ks * CHUNK;
    __shared__ __align__(16) float xs[64 * 256];  // (c,m) at c*256 + ((m>>2)^(c&15))*4 + (m&3)
    __shared__ float rs_part[4][64];
    int tid = threadIdx.x;
    int lane = tid & 63, wv = tid >> 6;
    const float* xb = x + ((size_t)b * 64) * 4096 + m0;

    // Stage: each wave loads 16 channel rows; lane l handles m-block l (float4)
    #pragma unroll
    for (int r = 0; r < 16; ++r) {
        int c = wv * 16 + r;
        float4 v = *reinterpret_cast<const float4*>(xb + (size_t)c * 4096 + lane * 4);
        int mb = lane ^ (c & 15);
        *reinterpret_cast<float4*>(&xs[c * 256 + mb * 4]) = v;
    }
    __syncthreads();

    // Register-tiled rank-4 updates: thread (ty,tx) owns rows 4ty.., cols 4tx..
    int tx = tid & 15, ty = tid >> 4;
    float acc[4][4] = {};
    for (int mb = 0; mb < 64; ++mb) {
        float4 av[4], bv[4];
        #pragma unroll
        for (int a = 0; a < 4; ++a) {
            int ci = ty * 4 + a;
            av[a] = *reinterpret_cast<const float4*>(&xs[ci * 256 + ((mb ^ (ci & 15)) << 2)]);
        }
        #pragma unroll
        for (int q = 0; q < 4; ++q) {
            int cj = tx * 4 + q;
            bv[q] = *reinterpret_cast<const float4*>(&xs[cj * 256 + ((mb ^ (cj & 15)) << 2)]);
        }
        #pragma unroll
        for (int a = 0; a < 4; ++a)
            #pragma unroll
            for (int q = 0; q < 4; ++q)
                acc[a][q] += av[a].x * bv[q].x + av[a].y * bv[q].y +
                             av[a].z * bv[q].z + av[a].w * bv[q].w;
    }

    float* outp = ws + (size_t)blk * PART_STRIDE;
    #pragma unroll
    for (int a = 0; a < 4; ++a)
        *reinterpret_cast<float4*>(&outp[(ty * 4 + a) * 64 + tx * 4]) =
            make_float4(acc[a][0], acc[a][1], acc[a][2], acc[a][3]);

    // Partial row sums (quarter-row per thread, then combine)
    {
        int i = tid & 63, q = tid >> 6;
        float s = 0.f;
        for (int mb = q * 16; mb < q * 16 + 16; ++mb) {
            float4 v = *reinterpret_cast<const float4*>(&xs[i * 256 + ((mb ^ (i & 15)) << 2)]);
            s += v.x + v.y + v.z + v.w;
        }
        rs_part[q][i] = s;
    }
    __syncthreads();
    if (tid < 64)
        outp[4096 + tid] = rs_part[0][tid] + rs_part[1][tid] + rs_part[2][tid] + rs_part[3][tid];
}

// ---------------------------------------------------------------------------
// 64x64x64 fp32 matmul in LDS, D = A^T @ B (== A@B since all NS iterates are
// symmetric). Row index k is wave-uniform -> both float4 reads conflict-free.
// One block = 256 threads, thread (ty,tx) computes a 4x4 tile.
// ---------------------------------------------------------------------------
__device__ __forceinline__ void mm64(float* __restrict__ D, const float* __restrict__ A,
                                     const float* __restrict__ B, int tid) {
    int tx = tid & 15, ty = tid >> 4;
    float acc[4][4] = {};
    #pragma unroll 4
    for (int k = 0; k < 64; ++k) {
        float4 av = *reinterpret_cast<const float4*>(&A[k * 64 + ty * 4]);
        float4 bv = *reinterpret_cast<const float4*>(&B[k * 64 + tx * 4]);
        float aa[4] = {av.x, av.y, av.z, av.w};
        float bb[4] = {bv.x, bv.y, bv.z, bv.w};
        #pragma unroll
        for (int a = 0; a < 4; ++a)
            #pragma unroll
            for (int q = 0; q < 4; ++q)
                acc[a][q] += aa[a] * bb[q];
    }
    #pragma unroll
    for (int a = 0; a < 4; ++a)
        *reinterpret_cast<float4*>(&D[(ty * 4 + a) * 64 + tx * 4]) =
            make_float4(acc[a][0], acc[a][1], acc[a][2], acc[a][3]);
    __syncthreads();
}

// ---------------------------------------------------------------------------
// K2: one block per batch. Reduce split-K partials -> cov -> Newton-Schulz
// (iterN=5) -> column means -> conv(center tap) -> relu -> conv -> sigmoid.
// ---------------------------------------------------------------------------
__global__ __launch_bounds__(256) void ns_kernel(const float* __restrict__ wsin,
                                                 const float* __restrict__ w1,
                                                 const float* __restrict__ b1,
                                                 const float* __restrict__ w2,
                                                 const float* __restrict__ b2,
                                                 float* __restrict__ s_out) {
    __shared__ __align__(16) float buf[5][4096];
    __shared__ float w1t[64 * 65];  // transposed center taps, stride 65 (bank spread)
    __shared__ float w2t[64 * 65];
    __shared__ float red[256];
    __shared__ float rsum[64];
    __shared__ float ych[64];
    __shared__ float hid[64];
    int b = blockIdx.x, tid = threadIdx.x;

    {   // conv center taps w[o][i][1][1], stored [i][o]
        int o = tid & 63, g = tid >> 6;
        for (int q = 0; q < 16; ++q) {
            int i = g * 16 + q;
            w1t[i * 65 + o] = w1[(o * 64 + i) * 9 + 4];
            w2t[i * 65 + o] = w2[(o * 64 + i) * 9 + 4];
        }
    }

    // Reduce split-K partials
    const float* base = wsin + (size_t)b * KS * PART_STRIDE;
    for (int q = 0; q < 16; ++q) {
        int e = q * 256 + tid;
        float s = 0.f;
        for (int k = 0; k < KS; ++k) s += base[k * PART_STRIDE + e];
        buf[0][e] = s;                              // raw S_ij
    }
    if (tid < 64) {
        float s = 0.f;
        for (int k = 0; k < KS; ++k) s += base[k * PART_STRIDE + 4096 + tid];
        rsum[tid] = s;                              // row sums
    }
    __syncthreads();

    // cov_ij = S_ij/M - mu_i*mu_j ; normA = sum(cov)
    const float invM = 1.0f / 4096.0f;
    float lsum = 0.f;
    for (int q = 0; q < 16; ++q) {
        int e = q * 256 + tid;
        int i = e >> 6, j = e & 63;
        float cv = buf[0][e] * invM - (rsum[i] * invM) * (rsum[j] * invM);
        buf[0][e] = cv;
        lsum += cv;
    }
    red[tid] = lsum;
    __syncthreads();
    for (int s = 128; s > 0; s >>= 1) {
        if (tid < s) red[tid] += red[tid + s];
        __syncthreads();
    }
    const float normA = red[0];
    const float invNA = 1.0f / normA;

    // buf0 = A = cov/normA ; buf1 = ZY0 = 0.5*(3I - A)
    for (int q = 0; q < 16; ++q) {
        int e = q * 256 + tid;
        int i = e >> 6, j = e & 63;
        float a = buf[0][e] * invNA;
        buf[0][e] = a;
        buf[1][e] = 0.5f * ((i == j ? 3.0f : 0.0f) - a);
    }
    __syncthreads();

    mm64(buf[2], buf[0], buf[1], tid);   // Y = A @ ZY0 ; Z = buf1
    int yi = 2, zi = 1, f0 = 0, f1 = 3, f2 = 4;
    for (int it = 0; it < 3; ++it) {
        mm64(buf[f0], buf[zi], buf[yi], tid);        // T = Z@Y
        for (int q = 0; q < 16; ++q) {               // W = 0.5*(3I - T), in place
            int e = q * 256 + tid;
            int i = e >> 6, j = e & 63;
            buf[f0][e] = 0.5f * ((i == j ? 3.0f : 0.0f) - buf[f0][e]);
        }
        __syncthreads();
        mm64(buf[f1], buf[yi], buf[f0], tid);        // Ynew = Y@W
        mm64(buf[f2], buf[f0], buf[zi], tid);        // Znew = W@Z
        int nyi = f1, nzi = f2;
        f1 = yi; f2 = zi; yi = nyi; zi = nzi;        // rotate buffers
    }
    mm64(buf[f0], buf[zi], buf[yi], tid);            // T = Z@Y
    for (int q = 0; q < 16; ++q) {                   // (3I - T), no 0.5 (folded below)
        int e = q * 256 + tid;
        int i = e >> 6, j = e & 63;
        buf[f0][e] = (i == j ? 3.0f : 0.0f) - buf[f0][e];
    }
    __syncthreads();
    mm64(buf[f1], buf[yi], buf[f0], tid);            // YU = Y @ (3I - T)

    // y_chan[j] = mean_i( 0.5*YU[i][j] ) * sqrt(normA)
    if (tid < 64) {
        float s = 0.f;
        for (int i = 0; i < 64; ++i) s += buf[f1][i * 64 + tid];
        ych[tid] = s * (0.5f / 64.0f) * sqrtf(normA);
    }
    __syncthreads();
    if (tid < 64) {
        float t1 = b1[tid];
        for (int i = 0; i < 64; ++i) t1 += w1t[i * 65 + tid] * ych[i];
        hid[tid] = fmaxf(t1, 0.f);
    }
    __syncthreads();
    if (tid < 64) {
        float t2 = b2[tid];
        for (int i = 0; i < 64; ++i) t2 += w2t[i * 65 + tid] * hid[i];
        s_out[b * 64 + tid] = 1.0f / (1.0f + expf(-t2));
    }
}

// ---------------------------------------------------------------------------
// K3: out[b,c,h,w] = s[b,c] * x[b,c,h,w], float4 grid-stride
// ---------------------------------------------------------------------------
__global__ __launch_bounds__(256) void scale_kernel(const float* __restrict__ x,
                                                    const float* __restrict__ s,
                                                    float* __restrict__ out, int n4) {
    int idx = blockIdx.x * 256 + threadIdx.x;
    int stride = gridDim.x * 256;
    for (int f = idx; f < n4; f += stride) {
        float sv = s[f >> 10];   // 1024 float4 per (b,c) plane; f>>10 == b*64+c
        float4 v = reinterpret_cast<const float4*>(x)[f];
        reinterpret_cast<float4*>(out)[f] = make_float4(v.x * sv, v.y * sv, v.z * sv, v.w * sv);
    }
}

extern "C" void kernel_launch(void* const* d_in, const int* in_sizes, int n_in,
                              void* d_out, int out_size, void* d_ws, size_t ws_size,
                              hipStream_t stream) {
    const float* x  = (const float*)d_in[0];
    const float* w1 = (const float*)d_in[1];
    const float* b1 = (const float*)d_in[2];
    const float* w2 = (const float*)d_in[3];
    const float* b2 = (const float*)d_in[4];
    float* out = (float*)d_out;
    float* ws  = (float*)d_ws;
    float* s_area = ws + (size_t)256 * PART_STRIDE;   // 16*64 sigmoid scales

    cov_partial_kernel<<<dim3(256), dim3(256), 0, stream>>>(x, ws);
    ns_kernel<<<dim3(16), dim3(256), 0, stream>>>(ws, w1, b1, w2, b2, s_area);
    scale_kernel<<<dim3(2048), dim3(256), 0, stream>>>(x, s_area, out, 1048576);
}

// Round 2
// 50.909 us; speedup vs baseline: 1.3607x; 1.3607x over previous
//
#include <hip/hip_runtime.h>
#include <math.h>

// Problem constants: B=16, C=64, H=W=64, M=4096
#define KS 16            // split-K chunks per batch in cov kernel
#define CHUNK 256        // m-columns per chunk
#define PART_STRIDE 4160 // 64*64 partial S + 64 partial rowsums

typedef __attribute__((ext_vector_type(8))) short short8;
typedef __attribute__((ext_vector_type(4))) float floatx4;

__device__ __forceinline__ unsigned short f2bf(float f) {
    unsigned int u = __float_as_uint(f);
    unsigned int r = (u + 0x7fffu + ((u >> 16) & 1u)) >> 16;  // RNE
    return (unsigned short)r;
}
__device__ __forceinline__ float bf2f(unsigned short h) {
    return __uint_as_float(((unsigned int)h) << 16);
}

// ---------------------------------------------------------------------------
// K1: per-(batch, chunk) partial Gram matrix + partial row sums (unchanged).
// ---------------------------------------------------------------------------
__global__ __launch_bounds__(256) void cov_partial_kernel(const float* __restrict__ x,
                                                          float* __restrict__ ws) {
    int blk = blockIdx.x;          // b*16 + ks
    int b = blk >> 4, ks = blk & 15;
    int m0 = ks * CHUNK;
    __shared__ __align__(16) float xs[64 * 256];
    __shared__ float rs_part[4][64];
    int tid = threadIdx.x;
    int lane = tid & 63, wv = tid >> 6;
    const float* xb = x + ((size_t)b * 64) * 4096 + m0;

    #pragma unroll
    for (int r = 0; r < 16; ++r) {
        int c = wv * 16 + r;
        float4 v = *reinterpret_cast<const float4*>(xb + (size_t)c * 4096 + lane * 4);
        int mb = lane ^ (c & 15);
        *reinterpret_cast<float4*>(&xs[c * 256 + mb * 4]) = v;
    }
    __syncthreads();

    int tx = tid & 15, ty = tid >> 4;
    float acc[4][4] = {};
    for (int mb = 0; mb < 64; ++mb) {
        float4 av[4], bv[4];
        #pragma unroll
        for (int a = 0; a < 4; ++a) {
            int ci = ty * 4 + a;
            av[a] = *reinterpret_cast<const float4*>(&xs[ci * 256 + ((mb ^ (ci & 15)) << 2)]);
        }
        #pragma unroll
        for (int q = 0; q < 4; ++q) {
            int cj = tx * 4 + q;
            bv[q] = *reinterpret_cast<const float4*>(&xs[cj * 256 + ((mb ^ (cj & 15)) << 2)]);
        }
        #pragma unroll
        for (int a = 0; a < 4; ++a)
            #pragma unroll
            for (int q = 0; q < 4; ++q)
                acc[a][q] += av[a].x * bv[q].x + av[a].y * bv[q].y +
                             av[a].z * bv[q].z + av[a].w * bv[q].w;
    }

    float* outp = ws + (size_t)blk * PART_STRIDE;
    #pragma unroll
    for (int a = 0; a < 4; ++a)
        *reinterpret_cast<float4*>(&outp[(ty * 4 + a) * 64 + tx * 4]) =
            make_float4(acc[a][0], acc[a][1], acc[a][2], acc[a][3]);

    {
        int i = tid & 63, q = tid >> 6;
        float s = 0.f;
        for (int mb = q * 16; mb < q * 16 + 16; ++mb) {
            float4 v = *reinterpret_cast<const float4*>(&xs[i * 256 + ((mb ^ (i & 15)) << 2)]);
            s += v.x + v.y + v.z + v.w;
        }
        rs_part[q][i] = s;
    }
    __syncthreads();
    if (tid < 64)
        outp[4096 + tid] = rs_part[0][tid] + rs_part[1][tid] + rs_part[2][tid] + rs_part[3][tid];
}

// ---------------------------------------------------------------------------
// K2: Newton-Schulz on matrix cores.
// Each 64x64 matrix is stored as hi+lo bf16 planes in k-major fragment layout:
//   elem (r,k) at halfword ((k>>3)*64 + r)*8 + (k&7)   (16B row stride)
// A-fragment (16x16x32 MFMA) for tile-row tr, k-step ks: lane l reads 8
// contiguous bf16 at ((4*ks + (l>>4))*64 + 16*tr + (l&15))*8 -> ds_read_b128.
// All NS iterates are symmetric, so the SAME layout serves the B operand.
// Product P = (Uh+Ul)(Vh+Vl) ~= UhVh + UhVl + UlVh, fp32 MFMA accumulate.
// ---------------------------------------------------------------------------
__device__ __forceinline__ floatx4 mfma_bf16(short8 a, short8 b, floatx4 c) {
    return __builtin_amdgcn_mfma_f32_16x16x32_bf16(a, b, c, 0, 0, 0);
}

// MODE 0: D = 0.5*(3I - P)   MODE 1: D = P   MODE 2: D = (3I - P)
// MODE 3: column-sum of P into colsum[64] (D unused)
template <int MODE>
__device__ __forceinline__ void mm_pass(const unsigned short (*U)[4096],
                                        const unsigned short (*V)[4096],
                                        unsigned short (*D)[4096],
                                        float* colsum, int tid) {
    int lane = tid & 63, wv = tid >> 6;
    int g = lane >> 4, rh = lane & 15;
    int tr0 = (wv >> 1) * 2, tc0 = (wv & 1) * 2;   // 2x2 tiles of 16x16 per wave
    floatx4 acc[2][2];
    #pragma unroll
    for (int a = 0; a < 2; ++a)
        #pragma unroll
        for (int c = 0; c < 2; ++c)
            acc[a][c] = (floatx4){0.f, 0.f, 0.f, 0.f};

    #pragma unroll
    for (int ks = 0; ks < 2; ++ks) {
        int boff = ((4 * ks + g) * 64 + rh) * 8;
        short8 auh[2], aul[2], bvh[2], bvl[2];
        #pragma unroll
        for (int a = 0; a < 2; ++a) {
            int o = boff + (16 * (tr0 + a)) * 8;
            auh[a] = *reinterpret_cast<const short8*>(&U[0][o]);
            aul[a] = *reinterpret_cast<const short8*>(&U[1][o]);
        }
        #pragma unroll
        for (int c = 0; c < 2; ++c) {
            int o = boff + (16 * (tc0 + c)) * 8;
            bvh[c] = *reinterpret_cast<const short8*>(&V[0][o]);
            bvl[c] = *reinterpret_cast<const short8*>(&V[1][o]);
        }
        #pragma unroll
        for (int a = 0; a < 2; ++a)
            #pragma unroll
            for (int c = 0; c < 2; ++c) {
                acc[a][c] = mfma_bf16(auh[a], bvh[c], acc[a][c]);
                acc[a][c] = mfma_bf16(auh[a], bvl[c], acc[a][c]);
                acc[a][c] = mfma_bf16(aul[a], bvh[c], acc[a][c]);
            }
    }

    if (MODE == 3) {
        #pragma unroll
        for (int c = 0; c < 2; ++c) {
            float s = 0.f;
            #pragma unroll
            for (int a = 0; a < 2; ++a)
                s += acc[a][c].x + acc[a][c].y + acc[a][c].z + acc[a][c].w;
            atomicAdd(&colsum[16 * (tc0 + c) + rh], s);
        }
    } else {
        #pragma unroll
        for (int a = 0; a < 2; ++a)
            #pragma unroll
            for (int c = 0; c < 2; ++c) {
                int j = 16 * (tc0 + c) + rh;
                #pragma unroll
                for (int q = 0; q < 4; ++q) {
                    int i = 16 * (tr0 + a) + 4 * g + q;
                    float v = acc[a][c][q];
                    if (MODE == 0) v = 0.5f * ((i == j ? 3.0f : 0.0f) - v);
                    if (MODE == 2) v = ((i == j ? 3.0f : 0.0f) - v);
                    unsigned short h = f2bf(v);
                    int idx = ((j >> 3) * 64 + i) * 8 + (j & 7);
                    D[0][idx] = h;
                    D[1][idx] = f2bf(v - bf2f(h));
                }
            }
    }
    __syncthreads();
}

__global__ __launch_bounds__(256) void ns_kernel(const float* __restrict__ wsin,
                                                 const float* __restrict__ w1,
                                                 const float* __restrict__ b1,
                                                 const float* __restrict__ w2,
                                                 const float* __restrict__ b2,
                                                 float* __restrict__ s_out) {
    __shared__ __align__(16) float buf[4096];                    // fp32 cov scratch
    __shared__ __align__(16) unsigned short planes[5][2][4096];  // 5 slots x hi/lo
    __shared__ float w1t[64 * 65];
    __shared__ float w2t[64 * 65];
    __shared__ float red[256];
    __shared__ float rsum[64];
    __shared__ float ych[64];
    __shared__ float hid[64];
    __shared__ float colsum[64];
    int b = blockIdx.x, tid = threadIdx.x;

    if (tid < 64) colsum[tid] = 0.f;

    {   // conv center taps w[o][i][1][1], stored [i][o]
        int o = tid & 63, g = tid >> 6;
        for (int q = 0; q < 16; ++q) {
            int i = g * 16 + q;
            w1t[i * 65 + o] = w1[(o * 64 + i) * 9 + 4];
            w2t[i * 65 + o] = w2[(o * 64 + i) * 9 + 4];
        }
    }

    // Row sums first (needed for fused cov build)
    const float* base = wsin + (size_t)b * KS * PART_STRIDE;
    if (tid < 64) {
        float s = 0.f;
        for (int k = 0; k < KS; ++k) s += base[k * PART_STRIDE + 4096 + tid];
        rsum[tid] = s;
    }
    __syncthreads();

    // Reduce split-K partials (float4) fused with centering: cov = S/M - mu mu^T
    const float invM = 1.0f / 4096.0f;
    float lsum = 0.f;
    #pragma unroll
    for (int r = 0; r < 4; ++r) {
        int c4 = r * 256 + tid;            // float4 chunk 0..1023
        int e = c4 * 4;
        int i = e >> 6, j = e & 63;
        floatx4 s4 = (floatx4){0.f, 0.f, 0.f, 0.f};
        for (int k = 0; k < KS; ++k)
            s4 += *reinterpret_cast<const floatx4*>(base + k * PART_STRIDE + e);
        float mui = rsum[i] * invM;
        floatx4 cv;
        #pragma unroll
        for (int q = 0; q < 4; ++q) cv[q] = s4[q] * invM - mui * (rsum[j + q] * invM);
        *reinterpret_cast<floatx4*>(&buf[e]) = cv;
        lsum += cv[0] + cv[1] + cv[2] + cv[3];
    }
    red[tid] = lsum;
    __syncthreads();
    for (int s = 128; s > 0; s >>= 1) {
        if (tid < s) red[tid] += red[tid + s];
        __syncthreads();
    }
    const float normA = red[0];
    const float invNA = 1.0f / normA;

    // Convert A = cov/normA -> slot0, ZY0 = 0.5*(3I - A) -> slot1 (b64-packed writes)
    {
        int ci = tid >> 2, cj0 = (tid & 3) * 16;   // row ci, cols cj0..cj0+15
        #pragma unroll
        for (int g4 = 0; g4 < 4; ++g4) {
            int j = cj0 + g4 * 4;
            unsigned short ah[4], al_[4], zh[4], zl[4];
            #pragma unroll
            for (int q = 0; q < 4; ++q) {
                float a = buf[ci * 64 + j + q] * invNA;
                float zy = 0.5f * ((ci == j + q ? 3.0f : 0.0f) - a);
                unsigned short h = f2bf(a);
                ah[q] = h; al_[q] = f2bf(a - bf2f(h));
                h = f2bf(zy);
                zh[q] = h; zl[q] = f2bf(zy - bf2f(h));
            }
            int idx = ((j >> 3) * 64 + ci) * 8 + (j & 7);
            uint2 u;
            u.x = (unsigned)ah[0] | ((unsigned)ah[1] << 16);
            u.y = (unsigned)ah[2] | ((unsigned)ah[3] << 16);
            *reinterpret_cast<uint2*>(&planes[0][0][idx]) = u;
            u.x = (unsigned)al_[0] | ((unsigned)al_[1] << 16);
            u.y = (unsigned)al_[2] | ((unsigned)al_[3] << 16);
            *reinterpret_cast<uint2*>(&planes[0][1][idx]) = u;
            u.x = (unsigned)zh[0] | ((unsigned)zh[1] << 16);
            u.y = (unsigned)zh[2] | ((unsigned)zh[3] << 16);
            *reinterpret_cast<uint2*>(&planes[1][0][idx]) = u;
            u.x = (unsigned)zl[0] | ((unsigned)zl[1] << 16);
            u.y = (unsigned)zl[2] | ((unsigned)zl[3] << 16);
            *reinterpret_cast<uint2*>(&planes[1][1][idx]) = u;
        }
    }
    __syncthreads();

    // Newton-Schulz on MFMA. Y=slot2, Z=slot1, W scratch=slot0.
    mm_pass<1>(planes[0], planes[1], planes[2], colsum, tid);   // Y = A @ ZY0
    int yi = 2, zi = 1, f1 = 3, f2 = 4;
    for (int it = 0; it < 3; ++it) {
        mm_pass<0>(planes[zi], planes[yi], planes[0], colsum, tid);   // W = 0.5(3I - Z@Y)
        mm_pass<1>(planes[yi], planes[0], planes[f1], colsum, tid);   // Ynew = Y@W
        mm_pass<1>(planes[0], planes[zi], planes[f2], colsum, tid);   // Znew = W@Z
        int ny = f1, nz = f2; f1 = yi; f2 = zi; yi = ny; zi = nz;
    }
    mm_pass<2>(planes[zi], planes[yi], planes[0], colsum, tid);       // G = 3I - Z@Y
    mm_pass<3>(planes[yi], planes[0], planes[0], colsum, tid);        // colsum = sum_i (Y@G)

    // y_chan[j] = mean_i(0.5*YU[i][j]) * sqrt(normA), then conv-relu-conv-sigmoid
    if (tid < 64) {
        ych[tid] = colsum[tid] * (0.5f / 64.0f) * sqrtf(normA);
    }
    __syncthreads();
    if (tid < 64) {
        float t1 = b1[tid];
        for (int i = 0; i < 64; ++i) t1 += w1t[i * 65 + tid] * ych[i];
        hid[tid] = fmaxf(t1, 0.f);
    }
    __syncthreads();
    if (tid < 64) {
        float t2 = b2[tid];
        for (int i = 0; i < 64; ++i) t2 += w2t[i * 65 + tid] * hid[i];
        s_out[b * 64 + tid] = 1.0f / (1.0f + expf(-t2));
    }
}

// ---------------------------------------------------------------------------
// K3: out[b,c,h,w] = s[b,c] * x[b,c,h,w], float4 grid-stride (unchanged)
// ---------------------------------------------------------------------------
__global__ __launch_bounds__(256) void scale_kernel(const float* __restrict__ x,
                                                    const float* __restrict__ s,
                                                    float* __restrict__ out, int n4) {
    int idx = blockIdx.x * 256 + threadIdx.x;
    int stride = gridDim.x * 256;
    for (int f = idx; f < n4; f += stride) {
        float sv = s[f >> 10];
        float4 v = reinterpret_cast<const float4*>(x)[f];
        reinterpret_cast<float4*>(out)[f] = make_float4(v.x * sv, v.y * sv, v.z * sv, v.w * sv);
    }
}

extern "C" void kernel_launch(void* const* d_in, const int* in_sizes, int n_in,
                              void* d_out, int out_size, void* d_ws, size_t ws_size,
                              hipStream_t stream) {
    const float* x  = (const float*)d_in[0];
    const float* w1 = (const float*)d_in[1];
    const float* b1 = (const float*)d_in[2];
    const float* w2 = (const float*)d_in[3];
    const float* b2 = (const float*)d_in[4];
    float* out = (float*)d_out;
    float* ws  = (float*)d_ws;
    float* s_area = ws + (size_t)256 * PART_STRIDE;

    cov_partial_kernel<<<dim3(256), dim3(256), 0, stream>>>(x, ws);
    ns_kernel<<<dim3(16), dim3(256), 0, stream>>>(ws, w1, b1, w2, b2, s_area);
    scale_kernel<<<dim3(2048), dim3(256), 0, stream>>>(x, s_area, out, 1048576);
}

// Round 3
// 35.793 us; speedup vs baseline: 1.9354x; 1.4223x over previous
//
#include <hip/hip_runtime.h>
#include <math.h>

// Problem constants: B=16, C=64, H=W=64, M=4096
#define KS 16
#define CHUNK 256
#define PART_STRIDE 4160

typedef __attribute__((ext_vector_type(8))) short short8;
typedef __attribute__((ext_vector_type(4))) float floatx4;

__device__ __forceinline__ unsigned short f2bf(float f) {
    unsigned int u = __float_as_uint(f);
    return (unsigned short)((u + 0x7fffu + ((u >> 16) & 1u)) >> 16);  // RNE
}
__device__ __forceinline__ float bf2f(unsigned short h) {
    return __uint_as_float(((unsigned int)h) << 16);
}
// Halfword base of element (r, k=8*kb) in the swizzled fragment layout:
// row slot XOR'd by kb so staging writes spread banks; reads stay a
// permutation within the 16-row tile (conflict-free b128).
__device__ __forceinline__ int HW(int r, int kb) {
    return ((kb << 6) + (r ^ (kb & 15))) << 3;
}
__device__ __forceinline__ floatx4 mfma_bf16(short8 a, short8 b, floatx4 c) {
    return __builtin_amdgcn_mfma_f32_16x16x32_bf16(a, b, c, 0, 0, 0);
}

// ---------------------------------------------------------------------------
// K1: per-(batch, chunk) partial Gram via MFMA (split-bf16: XhXh'+XhXl'+XlXh')
// Partial S is symmetric -> store transposed positions so each lane's 4-run
// along i becomes a contiguous float4 global write.
// ---------------------------------------------------------------------------
__global__ __launch_bounds__(256) void cov_partial_kernel(const float* __restrict__ x,
                                                          float* __restrict__ ws) {
    __shared__ __align__(16) unsigned short xh[64 * CHUNK];
    __shared__ __align__(16) unsigned short xl[64 * CHUNK];
    __shared__ float rs_part[4][64];
    int blk = blockIdx.x, b = blk >> 4, ks = blk & 15;
    int tid = threadIdx.x, lane = tid & 63, wv = tid >> 6;
    const float* xb = x + ((size_t)b * 64) * 4096 + ks * CHUNK;

    // Stage: wave wv loads rows 16wv..16wv+15, lane covers cols 4*lane..+3
    int kbw = lane >> 1, wsub = (lane & 1) << 2;
    #pragma unroll
    for (int r = 0; r < 16; ++r) {
        int c = wv * 16 + r;
        float4 v = *reinterpret_cast<const float4*>(xb + (size_t)c * 4096 + lane * 4);
        float vv[4] = {v.x, v.y, v.z, v.w};
        unsigned short hs[4], ls[4];
        #pragma unroll
        for (int q = 0; q < 4; ++q) {
            hs[q] = f2bf(vv[q]);
            ls[q] = f2bf(vv[q] - bf2f(hs[q]));
        }
        int idx = HW(c, kbw) + wsub;
        uint2 u;
        u.x = hs[0] | ((unsigned)hs[1] << 16); u.y = hs[2] | ((unsigned)hs[3] << 16);
        *reinterpret_cast<uint2*>(&xh[idx]) = u;
        u.x = ls[0] | ((unsigned)ls[1] << 16); u.y = ls[2] | ((unsigned)ls[3] << 16);
        *reinterpret_cast<uint2*>(&xl[idx]) = u;
    }
    __syncthreads();

    int g = lane >> 4, rh = lane & 15;
    int ta0 = (wv >> 1) << 1, tc0 = (wv & 1) << 1;   // 2x2 tiles of 16x16 per wave
    floatx4 acc[2][2];
    #pragma unroll
    for (int a = 0; a < 2; ++a)
        #pragma unroll
        for (int c = 0; c < 2; ++c)
            acc[a][c] = (floatx4){0.f, 0.f, 0.f, 0.f};

    #pragma unroll
    for (int ks_ = 0; ks_ < 8; ++ks_) {
        int kb = ks_ * 4 + g;
        short8 ah[2], al[2], bh[2], bl[2];
        #pragma unroll
        for (int a = 0; a < 2; ++a) {
            int o = HW(16 * (ta0 + a) + rh, kb);
            ah[a] = *reinterpret_cast<const short8*>(&xh[o]);
            al[a] = *reinterpret_cast<const short8*>(&xl[o]);
        }
        #pragma unroll
        for (int c = 0; c < 2; ++c) {
            int o = HW(16 * (tc0 + c) + rh, kb);
            bh[c] = *reinterpret_cast<const short8*>(&xh[o]);
            bl[c] = *reinterpret_cast<const short8*>(&xl[o]);
        }
        #pragma unroll
        for (int a = 0; a < 2; ++a)
            #pragma unroll
            for (int c = 0; c < 2; ++c) {
                acc[a][c] = mfma_bf16(ah[a], bh[c], acc[a][c]);
                acc[a][c] = mfma_bf16(ah[a], bl[c], acc[a][c]);
                acc[a][c] = mfma_bf16(al[a], bh[c], acc[a][c]);
            }
    }

    float* outp = ws + (size_t)blk * PART_STRIDE;
    #pragma unroll
    for (int a = 0; a < 2; ++a)
        #pragma unroll
        for (int c = 0; c < 2; ++c) {
            int j = 16 * (tc0 + c) + rh;
            int i0 = 16 * (ta0 + a) + 4 * g;
            *reinterpret_cast<float4*>(&outp[j * 64 + i0]) =
                make_float4(acc[a][c][0], acc[a][c][1], acc[a][c][2], acc[a][c][3]);
        }

    // Partial row sums from the staged planes
    {
        float s = 0.f;
        #pragma unroll
        for (int m = 0; m < 8; ++m) {
            int o = HW(lane, wv * 8 + m);
            short8 vh = *reinterpret_cast<const short8*>(&xh[o]);
            short8 vl = *reinterpret_cast<const short8*>(&xl[o]);
            #pragma unroll
            for (int e = 0; e < 8; ++e)
                s += bf2f((unsigned short)vh[e]) + bf2f((unsigned short)vl[e]);
        }
        rs_part[wv][lane] = s;
    }
    __syncthreads();
    if (tid < 64)
        outp[4096 + tid] = rs_part[0][tid] + rs_part[1][tid] + rs_part[2][tid] + rs_part[3][tid];
}

// ---------------------------------------------------------------------------
// K2 helpers: 64x64x64 symmetric mm on MFMA, 8 waves, 2 tiles/wave.
// Writeback stores P^T (valid: all iterates symmetric) -> contiguous b64.
// MODE 0: D = 0.5*(3I - P)   MODE 1: D = P
// ---------------------------------------------------------------------------
template <int MODE>
__device__ __forceinline__ void mm_pass(const unsigned short (*U)[4096],
                                        const unsigned short (*V)[4096],
                                        unsigned short (*D)[4096], int tid) {
    int lane = tid & 63, wv = tid >> 6;
    int g = lane >> 4, rh = lane & 15;
    int ta = wv & 3, tc0 = (wv >> 2) << 1;
    floatx4 acc[2];
    acc[0] = (floatx4){0.f, 0.f, 0.f, 0.f};
    acc[1] = (floatx4){0.f, 0.f, 0.f, 0.f};

    #pragma unroll
    for (int ks_ = 0; ks_ < 2; ++ks_) {
        int kb = ks_ * 4 + g;
        int ao = HW(16 * ta + rh, kb);
        short8 auh = *reinterpret_cast<const short8*>(&U[0][ao]);
        short8 aul = *reinterpret_cast<const short8*>(&U[1][ao]);
        #pragma unroll
        for (int c = 0; c < 2; ++c) {
            int bo = HW(16 * (tc0 + c) + rh, kb);
            short8 bvh = *reinterpret_cast<const short8*>(&V[0][bo]);
            short8 bvl = *reinterpret_cast<const short8*>(&V[1][bo]);
            acc[c] = mfma_bf16(auh, bvh, acc[c]);
            acc[c] = mfma_bf16(auh, bvl, acc[c]);
            acc[c] = mfma_bf16(aul, bvh, acc[c]);
        }
    }

    int kbi = 2 * ta + (g >> 1);       // i>>3 for this lane's 4-run
    int sub = (g & 1) << 2;            // i&7 base
    #pragma unroll
    for (int c = 0; c < 2; ++c) {
        int j = 16 * (tc0 + c) + rh;
        unsigned short hs[4], ls[4];
        #pragma unroll
        for (int q = 0; q < 4; ++q) {
            int i = 16 * ta + 4 * g + q;
            float v = acc[c][q];
            if (MODE == 0) v = 0.5f * ((i == j ? 3.0f : 0.0f) - v);
            hs[q] = f2bf(v);
            ls[q] = f2bf(v - bf2f(hs[q]));
        }
        int idx = HW(j, kbi) + sub;    // transposed position (j, i)
        uint2 u;
        u.x = hs[0] | ((unsigned)hs[1] << 16); u.y = hs[2] | ((unsigned)hs[3] << 16);
        *reinterpret_cast<uint2*>(&D[0][idx]) = u;
        u.x = ls[0] | ((unsigned)ls[1] << 16); u.y = ls[2] | ((unsigned)ls[3] << 16);
        *reinterpret_cast<uint2*>(&D[1][idx]) = u;
    }
    __syncthreads();
}

// ---------------------------------------------------------------------------
// K2: one block (512 thr) per batch. Reduce partials -> cov -> 10 MFMA mms
// (1 init + 3 iters x 3) -> matvec epilogue (colsum trick) -> conv chain.
// ---------------------------------------------------------------------------
__global__ __launch_bounds__(512) void ns_kernel(const float* __restrict__ wsin,
                                                 const float* __restrict__ w1,
                                                 const float* __restrict__ b1,
                                                 const float* __restrict__ w2,
                                                 const float* __restrict__ b2,
                                                 float* __restrict__ s_out) {
    __shared__ __align__(16) float buf[4096];
    __shared__ __align__(16) unsigned short planes[5][2][4096];
    __shared__ float w1t[64 * 65];
    __shared__ float w2t[64 * 65];
    __shared__ float red[512];
    __shared__ float part[8][64];
    __shared__ float rsum[64], uvec[64], tvec[64], wvec[64], ych[64], hid[64];
    int b = blockIdx.x, tid = threadIdx.x;

    {   // conv center taps w[o][i][1][1] -> [i][o]
        int o = tid & 63, g8 = tid >> 6;
        #pragma unroll
        for (int q = 0; q < 8; ++q) {
            int i = g8 * 8 + q;
            w1t[i * 65 + o] = w1[(o * 64 + i) * 9 + 4];
            w2t[i * 65 + o] = w2[(o * 64 + i) * 9 + 4];
        }
    }

    const float* base = wsin + (size_t)b * KS * PART_STRIDE;
    // pass1: raw split-K reduce (float4)
    #pragma unroll
    for (int r = 0; r < 2; ++r) {
        int e = (r * 512 + tid) * 4;
        floatx4 s4 = (floatx4){0.f, 0.f, 0.f, 0.f};
        for (int k = 0; k < KS; ++k)
            s4 += *reinterpret_cast<const floatx4*>(base + k * PART_STRIDE + e);
        *reinterpret_cast<floatx4*>(&buf[e]) = s4;
    }
    if (tid < 64) {
        float s = 0.f;
        for (int k = 0; k < KS; ++k) s += base[k * PART_STRIDE + 4096 + tid];
        rsum[tid] = s;
    }
    __syncthreads();

    // pass2: center cov = S/M - mu mu^T, accumulate normA
    const float invM = 1.0f / 4096.0f;
    float lsum = 0.f;
    #pragma unroll
    for (int r = 0; r < 2; ++r) {
        int e = (r * 512 + tid) * 4;
        int i = e >> 6, j = e & 63;
        floatx4 cv = *reinterpret_cast<const floatx4*>(&buf[e]);
        float mui = rsum[i] * invM;
        #pragma unroll
        for (int q = 0; q < 4; ++q) cv[q] = cv[q] * invM - mui * (rsum[j + q] * invM);
        *reinterpret_cast<floatx4*>(&buf[e]) = cv;
        lsum += cv[0] + cv[1] + cv[2] + cv[3];
    }
    red[tid] = lsum;
    __syncthreads();
    for (int s = 256; s > 0; s >>= 1) {
        if (tid < s) red[tid] += red[tid + s];
        __syncthreads();
    }
    const float normA = red[0];
    const float invNA = 1.0f / normA;

    // Convert A -> slot0, Z0 = 0.5*(3I - A) -> slot1 (b128 stores)
    {
        int r = tid >> 3, oct = tid & 7;
        short8 ah, al, zh, zl;
        #pragma unroll
        for (int q = 0; q < 8; ++q) {
            int j = oct * 8 + q;
            float a = buf[r * 64 + j] * invNA;
            float zy = 0.5f * ((r == j ? 3.0f : 0.0f) - a);
            unsigned short h = f2bf(a);
            ah[q] = (short)h; al[q] = (short)f2bf(a - bf2f(h));
            h = f2bf(zy);
            zh[q] = (short)h; zl[q] = (short)f2bf(zy - bf2f(h));
        }
        int idx = HW(r, oct);
        *reinterpret_cast<short8*>(&planes[0][0][idx]) = ah;
        *reinterpret_cast<short8*>(&planes[0][1][idx]) = al;
        *reinterpret_cast<short8*>(&planes[1][0][idx]) = zh;
        *reinterpret_cast<short8*>(&planes[1][1][idx]) = zl;
    }
    __syncthreads();

    // NS: Y0 = A@Z0; 3 iters of {W=0.5(3I-Z@Y); Y=Y@W; Z=W@Z}
    mm_pass<1>(planes[0], planes[1], planes[2], tid);
    int yi = 2, zi = 1, f1 = 3, f2 = 4;
    for (int it = 0; it < 3; ++it) {
        mm_pass<0>(planes[zi], planes[yi], planes[0], tid);
        mm_pass<1>(planes[yi], planes[0], planes[f1], tid);
        mm_pass<1>(planes[0], planes[zi], planes[f2], tid);
        int ny = f1, nz = f2;
        f1 = yi; f2 = zi; yi = ny; zi = nz;
    }

    // Epilogue: colsum(0.5*Y(3I-ZY)) = 0.5*(3u - Y(Zu)), u = colsum(Y)
    const unsigned short (*Y)[4096] = planes[yi];
    const unsigned short (*Z)[4096] = planes[zi];
    int ii = tid & 63, grp = tid >> 6;
    {
        int o = HW(ii, grp);
        short8 vh = *reinterpret_cast<const short8*>(&Y[0][o]);
        short8 vl = *reinterpret_cast<const short8*>(&Y[1][o]);
        float s = 0.f;
        #pragma unroll
        for (int e = 0; e < 8; ++e)
            s += bf2f((unsigned short)vh[e]) + bf2f((unsigned short)vl[e]);
        part[grp][ii] = s;
    }
    __syncthreads();
    if (tid < 64) {
        float s = 0.f;
        #pragma unroll
        for (int q = 0; q < 8; ++q) s += part[q][tid];
        uvec[tid] = s;
    }
    __syncthreads();
    {
        int o = HW(ii, grp);
        short8 vh = *reinterpret_cast<const short8*>(&Z[0][o]);
        short8 vl = *reinterpret_cast<const short8*>(&Z[1][o]);
        float s = 0.f;
        #pragma unroll
        for (int e = 0; e < 8; ++e)
            s += (bf2f((unsigned short)vh[e]) + bf2f((unsigned short)vl[e])) * uvec[grp * 8 + e];
        part[grp][ii] = s;
    }
    __syncthreads();
    if (tid < 64) {
        float s = 0.f;
        #pragma unroll
        for (int q = 0; q < 8; ++q) s += part[q][tid];
        tvec[tid] = s;
    }
    __syncthreads();
    {
        int o = HW(ii, grp);
        short8 vh = *reinterpret_cast<const short8*>(&Y[0][o]);
        short8 vl = *reinterpret_cast<const short8*>(&Y[1][o]);
        float s = 0.f;
        #pragma unroll
        for (int e = 0; e < 8; ++e)
            s += (bf2f((unsigned short)vh[e]) + bf2f((unsigned short)vl[e])) * tvec[grp * 8 + e];
        part[grp][ii] = s;
    }
    __syncthreads();
    if (tid < 64) {
        float s = 0.f;
        #pragma unroll
        for (int q = 0; q < 8; ++q) s += part[q][tid];
        wvec[tid] = s;
        ych[tid] = (3.0f * uvec[tid] - s) * (0.5f / 64.0f) * sqrtf(normA);
    }
    __syncthreads();
    if (tid < 64) {
        float t1 = b1[tid];
        for (int i = 0; i < 64; ++i) t1 += w1t[i * 65 + tid] * ych[i];
        hid[tid] = fmaxf(t1, 0.f);
    }
    __syncthreads();
    if (tid < 64) {
        float t2 = b2[tid];
        for (int i = 0; i < 64; ++i) t2 += w2t[i * 65 + tid] * hid[i];
        s_out[b * 64 + tid] = 1.0f / (1.0f + expf(-t2));
    }
}

// ---------------------------------------------------------------------------
// K3: out[b,c,h,w] = s[b,c] * x[b,c,h,w], float4 grid-stride
// ---------------------------------------------------------------------------
__global__ __launch_bounds__(256) void scale_kernel(const float* __restrict__ x,
                                                    const float* __restrict__ s,
                                                    float* __restrict__ out, int n4) {
    int idx = blockIdx.x * 256 + threadIdx.x;
    int stride = gridDim.x * 256;
    for (int f = idx; f < n4; f += stride) {
        float sv = s[f >> 10];
        float4 v = reinterpret_cast<const float4*>(x)[f];
        reinterpret_cast<float4*>(out)[f] = make_float4(v.x * sv, v.y * sv, v.z * sv, v.w * sv);
    }
}

extern "C" void kernel_launch(void* const* d_in, const int* in_sizes, int n_in,
                              void* d_out, int out_size, void* d_ws, size_t ws_size,
                              hipStream_t stream) {
    const float* x  = (const float*)d_in[0];
    const float* w1 = (const float*)d_in[1];
    const float* b1 = (const float*)d_in[2];
    const float* w2 = (const float*)d_in[3];
    const float* b2 = (const float*)d_in[4];
    float* out = (float*)d_out;
    float* ws  = (float*)d_ws;
    float* s_area = ws + (size_t)256 * PART_STRIDE;

    cov_partial_kernel<<<dim3(256), dim3(256), 0, stream>>>(x, ws);
    ns_kernel<<<dim3(16), dim3(512), 0, stream>>>(ws, w1, b1, w2, b2, s_area);
    scale_kernel<<<dim3(2048), dim3(256), 0, stream>>>(x, s_area, out, 1048576);
}